// Round 9
// baseline (16411.571 us; speedup 1.0000x reference)
//
#include <hip/hip_runtime.h>
#include <hip/hip_cooperative_groups.h>
#include <math.h>

namespace cg = cooperative_groups;

#define DD 512

typedef _Float16 half8v __attribute__((ext_vector_type(8)));
typedef __attribute__((ext_vector_type(4))) float f32x4;

__device__ __forceinline__ float sigm(float x) { return 1.0f / (1.0f + expf(-x)); }

// ---------- setup kernels (unchanged) ----------
__global__ void msd_gi_kernel(const float* __restrict__ emb,
                              const float* __restrict__ wf, const float* __restrict__ bf,
                              const float* __restrict__ ws_, const float* __restrict__ bs,
                              float* __restrict__ gif, float* __restrict__ gis)
{
    int t = blockIdx.x;
    int part = blockIdx.y;
    int net = part / 6;
    int j = (part % 6) * 256 + threadIdx.x;
    __shared__ float e[DD];
    for (int k = threadIdx.x; k < DD; k += 256) e[k] = emb[t * DD + k];
    __syncthreads();
    const float* w = net ? ws_ : wf;
    const float* b = net ? bs : bf;
    const float* wr = w + (size_t)j * DD;
    float acc = b[j];
    #pragma unroll 8
    for (int k = 0; k < DD; k += 4) {
        float4 wv = *reinterpret_cast<const float4*>(wr + k);
        acc = fmaf(wv.x, e[k], acc);
        acc = fmaf(wv.y, e[k + 1], acc);
        acc = fmaf(wv.z, e[k + 2], acc);
        acc = fmaf(wv.w, e[k + 3], acc);
    }
    (net ? gis : gif)[t * 1536 + j] = acc;
}

__global__ void msd_f2h_kernel(const float* __restrict__ in, _Float16* __restrict__ out, int n4)
{
    int i = blockIdx.x * 256 + threadIdx.x;
    if (i >= n4) return;
    float4 v = reinterpret_cast<const float4*>(in)[i];
    _Float16 o[4] = {(_Float16)v.x, (_Float16)v.y, (_Float16)v.z, (_Float16)v.w};
    *reinterpret_cast<ushort4*>(out + (size_t)i * 4) = *reinterpret_cast<ushort4*>(o);
}

__global__ void msd_init_kernel(const float* __restrict__ z, float* __restrict__ zf32,
                                float* __restrict__ zs32, _Float16* __restrict__ zf16,
                                _Float16* __restrict__ zs16, int n)
{
    int i = blockIdx.x * 256 + threadIdx.x;
    if (i < n) {
        float v = z[i];
        zf32[i] = v; zs32[i] = v;
        _Float16 h = (_Float16)v;
        zf16[i] = h; zs16[i] = h;
    }
}

// ---------- phase bodies (shared by coop kernel and fallback kernels) ----------
// 256 blocks x 256 threads (4 waves). All index math assumes that geometry.

// GRU: block tile 64 rows x 64 cols x 3 gates; wave tile 32x32x3 (2x2 waves).
__device__ __forceinline__ void phase_gru(
    int bid, int tid,
    const _Float16* __restrict__ A16, const float* __restrict__ H32,
    const _Float16* __restrict__ W, const float* __restrict__ bhh,
    const float* __restrict__ gi,
    _Float16* __restrict__ o16, float* __restrict__ o32, bool writeBoth)
{
    const int l = tid & 63, w = tid >> 6;
    const int lr = l & 15, hi = l >> 4;
    const int koff = hi * 8, er4 = hi * 4;
    const int rt = bid >> 3, ct = bid & 7;           // 32 x 8 = 256 jobs
    const int r0 = rt * 64 + (w & 1) * 32;
    const int c0 = ct * 64 + (w >> 1) * 32;

    const _Float16* pA0 = A16 + (size_t)(r0 + lr) * DD + koff;
    const _Float16* pA1 = pA0 + 16 * DD;
    const half8v* pR0 = (const half8v*)(W + (size_t)(c0 + lr) * DD + koff);
    const half8v* pR1 = (const half8v*)(W + (size_t)(c0 + 16 + lr) * DD + koff);
    const half8v* pZ0 = (const half8v*)(W + (size_t)(512 + c0 + lr) * DD + koff);
    const half8v* pZ1 = (const half8v*)(W + (size_t)(512 + c0 + 16 + lr) * DD + koff);
    const half8v* pN0 = (const half8v*)(W + (size_t)(1024 + c0 + lr) * DD + koff);
    const half8v* pN1 = (const half8v*)(W + (size_t)(1024 + c0 + 16 + lr) * DD + koff);

    f32x4 aR[2][2], aZ[2][2], aN[2][2];
    #pragma unroll
    for (int m = 0; m < 2; ++m)
        #pragma unroll
        for (int n = 0; n < 2; ++n) {
            aR[m][n] = (f32x4){0.f,0.f,0.f,0.f};
            aZ[m][n] = (f32x4){0.f,0.f,0.f,0.f};
            aN[m][n] = (f32x4){0.f,0.f,0.f,0.f};
        }

    #pragma unroll
    for (int kt = 0; kt < 16; ++kt) {
        half8v a0 = *(const half8v*)(pA0 + kt * 32);
        half8v a1 = *(const half8v*)(pA1 + kt * 32);
        half8v bR0 = pR0[kt*4], bR1 = pR1[kt*4];
        half8v bZ0 = pZ0[kt*4], bZ1 = pZ1[kt*4];
        half8v bN0 = pN0[kt*4], bN1 = pN1[kt*4];
        aR[0][0] = __builtin_amdgcn_mfma_f32_16x16x32_f16(a0, bR0, aR[0][0], 0,0,0);
        aR[0][1] = __builtin_amdgcn_mfma_f32_16x16x32_f16(a0, bR1, aR[0][1], 0,0,0);
        aR[1][0] = __builtin_amdgcn_mfma_f32_16x16x32_f16(a1, bR0, aR[1][0], 0,0,0);
        aR[1][1] = __builtin_amdgcn_mfma_f32_16x16x32_f16(a1, bR1, aR[1][1], 0,0,0);
        aZ[0][0] = __builtin_amdgcn_mfma_f32_16x16x32_f16(a0, bZ0, aZ[0][0], 0,0,0);
        aZ[0][1] = __builtin_amdgcn_mfma_f32_16x16x32_f16(a0, bZ1, aZ[0][1], 0,0,0);
        aZ[1][0] = __builtin_amdgcn_mfma_f32_16x16x32_f16(a1, bZ0, aZ[1][0], 0,0,0);
        aZ[1][1] = __builtin_amdgcn_mfma_f32_16x16x32_f16(a1, bZ1, aZ[1][1], 0,0,0);
        aN[0][0] = __builtin_amdgcn_mfma_f32_16x16x32_f16(a0, bN0, aN[0][0], 0,0,0);
        aN[0][1] = __builtin_amdgcn_mfma_f32_16x16x32_f16(a0, bN1, aN[0][1], 0,0,0);
        aN[1][0] = __builtin_amdgcn_mfma_f32_16x16x32_f16(a1, bN0, aN[1][0], 0,0,0);
        aN[1][1] = __builtin_amdgcn_mfma_f32_16x16x32_f16(a1, bN1, aN[1][1], 0,0,0);
    }

    #pragma unroll
    for (int n = 0; n < 2; ++n) {
        const int col = c0 + n * 16 + lr;
        const float gir = gi[col]        + bhh[col];
        const float giz = gi[col + 512]  + bhh[col + 512];
        const float gin = gi[col + 1024];
        const float bn  = bhh[col + 1024];
        #pragma unroll
        for (int m = 0; m < 2; ++m) {
            #pragma unroll
            for (int e = 0; e < 4; ++e) {
                const int row = r0 + m * 16 + er4 + e;
                float r_ = sigm(gir + aR[m][n][e]);
                float zg = sigm(giz + aZ[m][n][e]);
                float nn = tanhf(gin + r_ * (aN[m][n][e] + bn));
                float hv = H32[(size_t)row * DD + col];
                float o  = (1.f - zg) * nn + zg * hv;
                o16[(size_t)row * DD + col] = (_Float16)o;
                if (writeBoth) o32[(size_t)row * DD + col] = o;
            }
        }
    }
}

// Gate: block tile 64x64, K = 1024 (zfn then zs); wave 32x32. Adds bias here.
__device__ __forceinline__ void phase_gate(
    int bid, int tid,
    const _Float16* __restrict__ zfn16, const _Float16* __restrict__ zs16,
    const _Float16* __restrict__ gwh, const float* __restrict__ gb,
    float* __restrict__ glog)
{
    const int l = tid & 63, w = tid >> 6;
    const int lr = l & 15, hi = l >> 4;
    const int koff = hi * 8, er4 = hi * 4;
    const int rt = bid >> 3, ct = bid & 7;
    const int r0 = rt * 64 + (w & 1) * 32;
    const int c0 = ct * 64 + (w >> 1) * 32;

    const _Float16* pAf0 = zfn16 + (size_t)(r0 + lr) * DD + koff;
    const _Float16* pAf1 = pAf0 + 16 * DD;
    const _Float16* pAs0 = zs16 + (size_t)(r0 + lr) * DD + koff;
    const _Float16* pAs1 = pAs0 + 16 * DD;
    const half8v* pB0 = (const half8v*)(gwh + (size_t)(c0 + lr) * 1024 + koff);
    const half8v* pB1 = (const half8v*)(gwh + (size_t)(c0 + 16 + lr) * 1024 + koff);

    f32x4 a00 = {0,0,0,0}, a01 = {0,0,0,0}, a10 = {0,0,0,0}, a11 = {0,0,0,0};
    #pragma unroll
    for (int kt = 0; kt < 16; ++kt) {
        half8v a0 = *(const half8v*)(pAf0 + kt * 32);
        half8v a1 = *(const half8v*)(pAf1 + kt * 32);
        half8v b0 = pB0[kt * 4], b1 = pB1[kt * 4];
        a00 = __builtin_amdgcn_mfma_f32_16x16x32_f16(a0, b0, a00, 0,0,0);
        a01 = __builtin_amdgcn_mfma_f32_16x16x32_f16(a0, b1, a01, 0,0,0);
        a10 = __builtin_amdgcn_mfma_f32_16x16x32_f16(a1, b0, a10, 0,0,0);
        a11 = __builtin_amdgcn_mfma_f32_16x16x32_f16(a1, b1, a11, 0,0,0);
    }
    #pragma unroll
    for (int kt = 0; kt < 16; ++kt) {
        half8v a0 = *(const half8v*)(pAs0 + kt * 32);
        half8v a1 = *(const half8v*)(pAs1 + kt * 32);
        half8v b0 = pB0[64 + kt * 4], b1 = pB1[64 + kt * 4];
        a00 = __builtin_amdgcn_mfma_f32_16x16x32_f16(a0, b0, a00, 0,0,0);
        a01 = __builtin_amdgcn_mfma_f32_16x16x32_f16(a0, b1, a01, 0,0,0);
        a10 = __builtin_amdgcn_mfma_f32_16x16x32_f16(a1, b0, a10, 0,0,0);
        a11 = __builtin_amdgcn_mfma_f32_16x16x32_f16(a1, b1, a11, 0,0,0);
    }

    #pragma unroll
    for (int n = 0; n < 2; ++n) {
        const int col = c0 + n * 16 + lr;
        const float bias = gb[col];
        #pragma unroll
        for (int m = 0; m < 2; ++m) {
            f32x4 ac = m ? (n ? a11 : a10) : (n ? a01 : a00);
            #pragma unroll
            for (int e = 0; e < 4; ++e) {
                const int row = r0 + m * 16 + er4 + e;
                glog[(size_t)row * DD + col] = ac[e] + bias;
            }
        }
    }
}

// Fuse + LN: 8 rows/block, 2 rows/wave.
__device__ __forceinline__ void phase_ln(
    int bid, int tid,
    const float* __restrict__ glog, const _Float16* __restrict__ zfn16,
    const float* __restrict__ zs32, const float* __restrict__ gamma,
    const float* __restrict__ beta, float* __restrict__ zf32,
    _Float16* __restrict__ zf16, float* __restrict__ out, int T, int t)
{
    const int l = tid & 63, w = tid >> 6;
    #pragma unroll
    for (int rr = 0; rr < 2; ++rr) {
        const int row = bid * 8 + w * 2 + rr;
        const size_t grow = (size_t)row * DD;
        float p[8];
        float s = 0.f, s2 = 0.f;
        #pragma unroll
        for (int j = 0; j < 8; ++j) {
            const int c = l + j * 64;
            float g  = sigm(glog[grow + c]);
            float pv = g * (float)zfn16[grow + c] + (1.f - g) * zs32[grow + c] + zf32[grow + c];
            p[j] = pv; s += pv; s2 += pv * pv;
        }
        #pragma unroll
        for (int off = 1; off < 64; off <<= 1) {
            s  += __shfl_xor(s, off);
            s2 += __shfl_xor(s2, off);
        }
        const float mu  = s * (1.0f / DD);
        const float inv = rsqrtf(s2 * (1.0f / DD) - mu * mu + 1e-5f);
        float* op = out + ((size_t)row * T + t) * DD;
        #pragma unroll
        for (int j = 0; j < 8; ++j) {
            const int c = l + j * 64;
            float o = (p[j] - mu) * inv * gamma[c] + beta[c];
            __builtin_nontemporal_store(o, op + c);
            zf32[grow + c] = o;
            zf16[grow + c] = (_Float16)o;
        }
    }
}

// ---------- cooperative kernel: whole recurrence, 256 blocks ----------
__global__ __launch_bounds__(256, 2) void msd_coop(
    const _Float16* __restrict__ wfh, const _Float16* __restrict__ wsh,
    const _Float16* __restrict__ gwh,
    const float* __restrict__ bhhF, const float* __restrict__ bhhS,
    const float* __restrict__ gi_f, const float* __restrict__ gi_s,
    const float* __restrict__ gb, const float* __restrict__ gamma,
    const float* __restrict__ beta,
    float* __restrict__ zf32, _Float16* __restrict__ zf16,
    float* zs32a, _Float16* zs16a, float* zs32b, _Float16* zs16b,
    _Float16* __restrict__ zfn16, float* __restrict__ glog,
    float* __restrict__ out, int T)
{
    cg::grid_group grid = cg::this_grid();
    const int bid = blockIdx.x, tid = threadIdx.x;

    float*    zs32c = zs32a; float*    zs32n = zs32b;
    _Float16* zs16c = zs16a; _Float16* zs16n = zs16b;

    for (int t = 0; t < T; ++t) {
        const bool upd = (t & 1) == 0;
        const float* giF = gi_f + (size_t)t * 1536;
        const float* giS = gi_s + (size_t)t * 1536;

        phase_gru(bid, tid, zf16, zf32, wfh, bhhF, giF, zfn16, (float*)nullptr, false);
        if (upd)
            phase_gru(bid, tid, zs16c, zs32c, wsh, bhhS, giS, zs16n, zs32n, true);
        __threadfence();
        grid.sync();
        if (upd) {
            float* t1 = zs32c; zs32c = zs32n; zs32n = t1;
            _Float16* t2 = zs16c; zs16c = zs16n; zs16n = t2;
        }

        phase_gate(bid, tid, zfn16, zs16c, gwh, gb, glog);
        __threadfence();
        grid.sync();

        phase_ln(bid, tid, glog, zfn16, zs32c, gamma, beta, zf32, zf16, out, T, t);
        __threadfence();
        grid.sync();
    }
}

// ---------- fallback kernels (same bodies, per-step launches) ----------
__global__ __launch_bounds__(256, 2) void k_gru(
    const _Float16* zf16, const float* zf32,
    const _Float16* zs16c, const float* zs32c,
    const _Float16* wfh, const _Float16* wsh,
    const float* bhhF, const float* bhhS,
    const float* giF, const float* giS,
    _Float16* zfn16, _Float16* zs16n, float* zs32n)
{
    if (blockIdx.y == 0)
        phase_gru(blockIdx.x, threadIdx.x, zf16, zf32, wfh, bhhF, giF, zfn16, (float*)nullptr, false);
    else
        phase_gru(blockIdx.x, threadIdx.x, zs16c, zs32c, wsh, bhhS, giS, zs16n, zs32n, true);
}

__global__ __launch_bounds__(256, 2) void k_gate(
    const _Float16* zfn16, const _Float16* zs16,
    const _Float16* gwh, const float* gb, float* glog)
{
    phase_gate(blockIdx.x, threadIdx.x, zfn16, zs16, gwh, gb, glog);
}

__global__ __launch_bounds__(256, 2) void k_ln(
    const float* glog, const _Float16* zfn16, const float* zs32,
    const float* gamma, const float* beta,
    float* zf32, _Float16* zf16, float* out, int T, int t)
{
    phase_ln(blockIdx.x, threadIdx.x, glog, zfn16, zs32, gamma, beta, zf32, zf16, out, T, t);
}

extern "C" void kernel_launch(void* const* d_in, const int* in_sizes, int n_in,
                              void* d_out, int out_size, void* d_ws, size_t ws_size,
                              hipStream_t stream)
{
    const float* z_init = (const float*)d_in[0];
    const float* emb    = (const float*)d_in[1];
    const float* f_wih  = (const float*)d_in[2];
    const float* f_whh  = (const float*)d_in[3];
    const float* f_bih  = (const float*)d_in[4];
    const float* f_bhh  = (const float*)d_in[5];
    const float* s_wih  = (const float*)d_in[6];
    const float* s_whh  = (const float*)d_in[7];
    const float* s_bih  = (const float*)d_in[8];
    const float* s_bhh  = (const float*)d_in[9];
    const float* gw     = (const float*)d_in[10];
    const float* gb     = (const float*)d_in[11];
    const float* gamma  = (const float*)d_in[12];
    const float* beta   = (const float*)d_in[13];

    const int B = in_sizes[0] / DD;          // 2048
    int T = out_size / in_sizes[0];          // 64
    float* out = (float*)d_out;

    char* p = (char*)d_ws;
    auto alloc = [&](size_t bytes) { char* q = p; p += (bytes + 255) & ~(size_t)255; return q; };

    float* gi_f = (float*)alloc((size_t)T * 1536 * 4);
    float* gi_s = (float*)alloc((size_t)T * 1536 * 4);
    _Float16* wfh = (_Float16*)alloc((size_t)1536 * DD * 2);
    _Float16* wsh = (_Float16*)alloc((size_t)1536 * DD * 2);
    _Float16* gwh = (_Float16*)alloc((size_t)DD * 1024 * 2);
    size_t bd4 = (size_t)B * DD * 4;
    size_t bd2 = (size_t)B * DD * 2;
    float* zf32   = (float*)alloc(bd4);
    float* zs32a  = (float*)alloc(bd4);
    float* zs32b  = (float*)alloc(bd4);
    float* glog   = (float*)alloc(bd4);
    _Float16* zf16  = (_Float16*)alloc(bd2);
    _Float16* zs16a = (_Float16*)alloc(bd2);
    _Float16* zs16b = (_Float16*)alloc(bd2);
    _Float16* zfn16 = (_Float16*)alloc(bd2);

    msd_gi_kernel<<<dim3(T, 12), 256, 0, stream>>>(emb, f_wih, f_bih, s_wih, s_bih, gi_f, gi_s);
    msd_f2h_kernel<<<(1536 * DD / 4 + 255) / 256, 256, 0, stream>>>(f_whh, wfh, 1536 * DD / 4);
    msd_f2h_kernel<<<(1536 * DD / 4 + 255) / 256, 256, 0, stream>>>(s_whh, wsh, 1536 * DD / 4);
    msd_f2h_kernel<<<(DD * 1024 / 4 + 255) / 256, 256, 0, stream>>>(gw, gwh, DD * 1024 / 4);
    msd_init_kernel<<<(B * DD + 255) / 256, 256, 0, stream>>>(z_init, zf32, zs32a, zf16, zs16a, B * DD);

    void* args[] = {
        (void*)&wfh, (void*)&wsh, (void*)&gwh,
        (void*)&f_bhh, (void*)&s_bhh,
        (void*)&gi_f, (void*)&gi_s,
        (void*)&gb, (void*)&gamma, (void*)&beta,
        (void*)&zf32, (void*)&zf16,
        (void*)&zs32a, (void*)&zs16a, (void*)&zs32b, (void*)&zs16b,
        (void*)&zfn16, (void*)&glog,
        (void*)&out, (void*)&T
    };
    hipError_t err = hipLaunchCooperativeKernel((void*)msd_coop, dim3(256), dim3(256),
                                                args, 0, stream);
    if (err != hipSuccess) {
        // Fallback: identical math via per-step launches (3 dispatches/step).
        float*    zs32c = zs32a; float*    zs32n = zs32b;
        _Float16* zs16c = zs16a; _Float16* zs16n = zs16b;
        for (int t = 0; t < T; ++t) {
            const int upd = ((t & 1) == 0) ? 1 : 0;
            k_gru<<<dim3(256, 1 + upd), 256, 0, stream>>>(
                zf16, zf32, zs16c, zs32c, wfh, wsh, f_bhh, s_bhh,
                gi_f + (size_t)t * 1536, gi_s + (size_t)t * 1536,
                zfn16, zs16n, zs32n);
            if (upd) {
                float* t1 = zs32c; zs32c = zs32n; zs32n = t1;
                _Float16* t2 = zs16c; zs16c = zs16n; zs16n = t2;
            }
            k_gate<<<256, 256, 0, stream>>>(zfn16, zs16c, gwh, gb, glog);
            k_ln<<<256, 256, 0, stream>>>(glog, zfn16, zs32c, gamma, beta,
                                          zf32, zf16, out, T, t);
        }
    }
}

// Round 10
// 4647.438 us; speedup vs baseline: 3.5313x; 3.5313x over previous
//
#include <hip/hip_runtime.h>
#include <math.h>

#define DD 512

typedef _Float16 half8v __attribute__((ext_vector_type(8)));
typedef __attribute__((ext_vector_type(4))) float f32x4;

__device__ __forceinline__ float sigm(float x) { return 1.0f / (1.0f + expf(-x)); }

// ---------- setup kernels ----------
__global__ void msd_gi_kernel(const float* __restrict__ emb,
                              const float* __restrict__ wf, const float* __restrict__ bf,
                              const float* __restrict__ ws_, const float* __restrict__ bs,
                              float* __restrict__ gif, float* __restrict__ gis)
{
    int t = blockIdx.x;
    int part = blockIdx.y;
    int net = part / 6;
    int j = (part % 6) * 256 + threadIdx.x;
    __shared__ float e[DD];
    for (int k = threadIdx.x; k < DD; k += 256) e[k] = emb[t * DD + k];
    __syncthreads();
    const float* w = net ? ws_ : wf;
    const float* b = net ? bs : bf;
    const float* wr = w + (size_t)j * DD;
    float acc = b[j];
    #pragma unroll 8
    for (int k = 0; k < DD; k += 4) {
        float4 wv = *reinterpret_cast<const float4*>(wr + k);
        acc = fmaf(wv.x, e[k], acc);
        acc = fmaf(wv.y, e[k + 1], acc);
        acc = fmaf(wv.z, e[k + 2], acc);
        acc = fmaf(wv.w, e[k + 3], acc);
    }
    (net ? gis : gif)[t * 1536 + j] = acc;
}

__global__ void msd_f2h_kernel(const float* __restrict__ in, _Float16* __restrict__ out, int n4)
{
    int i = blockIdx.x * 256 + threadIdx.x;
    if (i >= n4) return;
    float4 v = reinterpret_cast<const float4*>(in)[i];
    _Float16 o[4] = {(_Float16)v.x, (_Float16)v.y, (_Float16)v.z, (_Float16)v.w};
    *reinterpret_cast<ushort4*>(out + (size_t)i * 4) = *reinterpret_cast<ushort4*>(o);
}

__global__ void msd_init_kernel(const float* __restrict__ z, float* __restrict__ zf32,
                                float* __restrict__ zs32, _Float16* __restrict__ zf16,
                                _Float16* __restrict__ zs16, int n)
{
    int i = blockIdx.x * 256 + threadIdx.x;
    if (i < n) {
        float v = z[i];
        zf32[i] = v; zs32[i] = v;
        _Float16 h = (_Float16)v;
        zf16[i] = h; zs16[i] = h;
    }
}

// ---------- K1: GRU step (R9-verified body, R3 geometry) ----------
// Block tile 64 rows x 64 cols x 3 gates; 4 waves (2x2) of 32x32x3.
// 1D job id: rt = bid>>3 (32 row tiles), ct = bid&7 (8 col tiles).
__device__ __forceinline__ void phase_gru(
    int bid, int tid,
    const _Float16* __restrict__ A16, const float* __restrict__ H32,
    const _Float16* __restrict__ W, const float* __restrict__ bhh,
    const float* __restrict__ gi,
    _Float16* __restrict__ o16, float* __restrict__ o32, bool writeBoth)
{
    const int l = tid & 63, w = tid >> 6;
    const int lr = l & 15, hi = l >> 4;
    const int koff = hi * 8, er4 = hi * 4;
    const int rt = bid >> 3, ct = bid & 7;
    const int r0 = rt * 64 + (w & 1) * 32;
    const int c0 = ct * 64 + (w >> 1) * 32;

    const _Float16* pA0 = A16 + (size_t)(r0 + lr) * DD + koff;
    const _Float16* pA1 = pA0 + 16 * DD;
    const half8v* pR0 = (const half8v*)(W + (size_t)(c0 + lr) * DD + koff);
    const half8v* pR1 = (const half8v*)(W + (size_t)(c0 + 16 + lr) * DD + koff);
    const half8v* pZ0 = (const half8v*)(W + (size_t)(512 + c0 + lr) * DD + koff);
    const half8v* pZ1 = (const half8v*)(W + (size_t)(512 + c0 + 16 + lr) * DD + koff);
    const half8v* pN0 = (const half8v*)(W + (size_t)(1024 + c0 + lr) * DD + koff);
    const half8v* pN1 = (const half8v*)(W + (size_t)(1024 + c0 + 16 + lr) * DD + koff);

    f32x4 aR[2][2], aZ[2][2], aN[2][2];
    #pragma unroll
    for (int m = 0; m < 2; ++m)
        #pragma unroll
        for (int n = 0; n < 2; ++n) {
            aR[m][n] = (f32x4){0.f,0.f,0.f,0.f};
            aZ[m][n] = (f32x4){0.f,0.f,0.f,0.f};
            aN[m][n] = (f32x4){0.f,0.f,0.f,0.f};
        }

    #pragma unroll
    for (int kt = 0; kt < 16; ++kt) {
        half8v a0 = *(const half8v*)(pA0 + kt * 32);
        half8v a1 = *(const half8v*)(pA1 + kt * 32);
        half8v bR0 = pR0[kt*4], bR1 = pR1[kt*4];
        half8v bZ0 = pZ0[kt*4], bZ1 = pZ1[kt*4];
        half8v bN0 = pN0[kt*4], bN1 = pN1[kt*4];
        aR[0][0] = __builtin_amdgcn_mfma_f32_16x16x32_f16(a0, bR0, aR[0][0], 0,0,0);
        aR[0][1] = __builtin_amdgcn_mfma_f32_16x16x32_f16(a0, bR1, aR[0][1], 0,0,0);
        aR[1][0] = __builtin_amdgcn_mfma_f32_16x16x32_f16(a1, bR0, aR[1][0], 0,0,0);
        aR[1][1] = __builtin_amdgcn_mfma_f32_16x16x32_f16(a1, bR1, aR[1][1], 0,0,0);
        aZ[0][0] = __builtin_amdgcn_mfma_f32_16x16x32_f16(a0, bZ0, aZ[0][0], 0,0,0);
        aZ[0][1] = __builtin_amdgcn_mfma_f32_16x16x32_f16(a0, bZ1, aZ[0][1], 0,0,0);
        aZ[1][0] = __builtin_amdgcn_mfma_f32_16x16x32_f16(a1, bZ0, aZ[1][0], 0,0,0);
        aZ[1][1] = __builtin_amdgcn_mfma_f32_16x16x32_f16(a1, bZ1, aZ[1][1], 0,0,0);
        aN[0][0] = __builtin_amdgcn_mfma_f32_16x16x32_f16(a0, bN0, aN[0][0], 0,0,0);
        aN[0][1] = __builtin_amdgcn_mfma_f32_16x16x32_f16(a0, bN1, aN[0][1], 0,0,0);
        aN[1][0] = __builtin_amdgcn_mfma_f32_16x16x32_f16(a1, bN0, aN[1][0], 0,0,0);
        aN[1][1] = __builtin_amdgcn_mfma_f32_16x16x32_f16(a1, bN1, aN[1][1], 0,0,0);
    }

    #pragma unroll
    for (int n = 0; n < 2; ++n) {
        const int col = c0 + n * 16 + lr;
        const float gir = gi[col]        + bhh[col];
        const float giz = gi[col + 512]  + bhh[col + 512];
        const float gin = gi[col + 1024];
        const float bn  = bhh[col + 1024];
        #pragma unroll
        for (int m = 0; m < 2; ++m) {
            #pragma unroll
            for (int e = 0; e < 4; ++e) {
                const int row = r0 + m * 16 + er4 + e;
                float r_ = sigm(gir + aR[m][n][e]);
                float zg = sigm(giz + aZ[m][n][e]);
                float nn = tanhf(gin + r_ * (aN[m][n][e] + bn));
                float hv = H32[(size_t)row * DD + col];
                float o  = (1.f - zg) * nn + zg * hv;
                o16[(size_t)row * DD + col] = (_Float16)o;
                if (writeBoth) o32[(size_t)row * DD + col] = o;
            }
        }
    }
}

__global__ __launch_bounds__(256, 2) void k_gru(
    const _Float16* zf16, const float* zf32,
    const _Float16* zs16c, const float* zs32c,
    const _Float16* wfh, const _Float16* wsh,
    const float* bhhF, const float* bhhS,
    const float* giF, const float* giS,
    _Float16* zfn16, _Float16* zs16n, float* zs32n)
{
    if (blockIdx.y == 0)
        phase_gru(blockIdx.x, threadIdx.x, zf16, zf32, wfh, bhhF, giF, zfn16, (float*)nullptr, false);
    else
        phase_gru(blockIdx.x, threadIdx.x, zs16c, zs32c, wsh, bhhS, giS, zs16n, zs32n, true);
}

// ---------- K2: gate GEMM (K=1024) + fuse + LayerNorm, fused ----------
// 128 blocks x 512 thr. Block = 16 rows x 512 cols; wave w -> cols [64w,64w+64).
// glog kept in LDS; LN = 2 rows per wave.
__global__ __launch_bounds__(512, 2) void k_gate_ln(
    const _Float16* __restrict__ zfn16, const _Float16* __restrict__ zs16,
    const float* __restrict__ zs32,
    const _Float16* __restrict__ gwh, const float* __restrict__ gb,
    const float* __restrict__ gamma, const float* __restrict__ beta,
    float* __restrict__ zf32, _Float16* __restrict__ zf16,
    float* __restrict__ out, int T, int t)
{
    __shared__ float sGlog[16][516];

    const int tid = threadIdx.x;
    const int l = tid & 63, w = tid >> 6;
    const int lr = l & 15, hi = l >> 4;
    const int koff = hi * 8, er4 = hi * 4;
    const int r0 = blockIdx.x * 16;
    const int c0 = w * 64;

    const _Float16* pAf = zfn16 + (size_t)(r0 + lr) * DD + koff;
    const _Float16* pAs = zs16  + (size_t)(r0 + lr) * DD + koff;
    const half8v* pB[4];
    #pragma unroll
    for (int n = 0; n < 4; ++n)
        pB[n] = (const half8v*)(gwh + (size_t)(c0 + n * 16 + lr) * 1024 + koff);

    f32x4 acc[4];
    #pragma unroll
    for (int n = 0; n < 4; ++n) acc[n] = (f32x4){0.f,0.f,0.f,0.f};

    // K 0..512: A = zfn16
    #pragma unroll
    for (int kt = 0; kt < 16; ++kt) {
        half8v a = *(const half8v*)(pAf + kt * 32);
        #pragma unroll
        for (int n = 0; n < 4; ++n)
            acc[n] = __builtin_amdgcn_mfma_f32_16x16x32_f16(a, pB[n][kt * 4], acc[n], 0,0,0);
    }
    // K 512..1024: A = zs16; B offset 512 elems = 64 half8v
    #pragma unroll
    for (int kt = 0; kt < 16; ++kt) {
        half8v a = *(const half8v*)(pAs + kt * 32);
        #pragma unroll
        for (int n = 0; n < 4; ++n)
            acc[n] = __builtin_amdgcn_mfma_f32_16x16x32_f16(a, pB[n][64 + kt * 4], acc[n], 0,0,0);
    }

    #pragma unroll
    for (int n = 0; n < 4; ++n) {
        const int col = c0 + n * 16 + lr;
        const float bias = gb[col];
        #pragma unroll
        for (int e = 0; e < 4; ++e)
            sGlog[er4 + e][col] = acc[n][e] + bias;
    }
    __syncthreads();

    // fuse + LN: wave w handles rows 2w, 2w+1
    #pragma unroll
    for (int rr = 0; rr < 2; ++rr) {
        const int row = w * 2 + rr;
        const size_t grow = (size_t)(r0 + row) * DD;
        float p[8];
        float s = 0.f, s2 = 0.f;
        #pragma unroll
        for (int j = 0; j < 8; ++j) {
            const int c = l + j * 64;
            float g  = sigm(sGlog[row][c]);
            float pv = g * (float)zfn16[grow + c] + (1.f - g) * zs32[grow + c] + zf32[grow + c];
            p[j] = pv; s += pv; s2 += pv * pv;
        }
        #pragma unroll
        for (int off = 1; off < 64; off <<= 1) {
            s  += __shfl_xor(s, off);
            s2 += __shfl_xor(s2, off);
        }
        const float mu  = s * (1.0f / DD);
        const float inv = rsqrtf(s2 * (1.0f / DD) - mu * mu + 1e-5f);
        float* op = out + ((size_t)(r0 + row) * T + t) * DD;
        #pragma unroll
        for (int j = 0; j < 8; ++j) {
            const int c = l + j * 64;
            float o = (p[j] - mu) * inv * gamma[c] + beta[c];
            __builtin_nontemporal_store(o, op + c);
            zf32[grow + c] = o;
            zf16[grow + c] = (_Float16)o;
        }
    }
}

extern "C" void kernel_launch(void* const* d_in, const int* in_sizes, int n_in,
                              void* d_out, int out_size, void* d_ws, size_t ws_size,
                              hipStream_t stream)
{
    const float* z_init = (const float*)d_in[0];
    const float* emb    = (const float*)d_in[1];
    const float* f_wih  = (const float*)d_in[2];
    const float* f_whh  = (const float*)d_in[3];
    const float* f_bih  = (const float*)d_in[4];
    const float* f_bhh  = (const float*)d_in[5];
    const float* s_wih  = (const float*)d_in[6];
    const float* s_whh  = (const float*)d_in[7];
    const float* s_bih  = (const float*)d_in[8];
    const float* s_bhh  = (const float*)d_in[9];
    const float* gw     = (const float*)d_in[10];
    const float* gb     = (const float*)d_in[11];
    const float* gamma  = (const float*)d_in[12];
    const float* beta   = (const float*)d_in[13];

    const int B = in_sizes[0] / DD;          // 2048
    int T = out_size / in_sizes[0];          // 64
    float* out = (float*)d_out;

    char* p = (char*)d_ws;
    auto alloc = [&](size_t bytes) { char* q = p; p += (bytes + 255) & ~(size_t)255; return q; };

    float* gi_f = (float*)alloc((size_t)T * 1536 * 4);
    float* gi_s = (float*)alloc((size_t)T * 1536 * 4);
    _Float16* wfh = (_Float16*)alloc((size_t)1536 * DD * 2);
    _Float16* wsh = (_Float16*)alloc((size_t)1536 * DD * 2);
    _Float16* gwh = (_Float16*)alloc((size_t)DD * 1024 * 2);
    size_t bd4 = (size_t)B * DD * 4;
    size_t bd2 = (size_t)B * DD * 2;
    float* zf32   = (float*)alloc(bd4);
    float* zs32a  = (float*)alloc(bd4);
    float* zs32b  = (float*)alloc(bd4);
    _Float16* zf16  = (_Float16*)alloc(bd2);
    _Float16* zs16a = (_Float16*)alloc(bd2);
    _Float16* zs16b = (_Float16*)alloc(bd2);
    _Float16* zfn16 = (_Float16*)alloc(bd2);

    msd_gi_kernel<<<dim3(T, 12), 256, 0, stream>>>(emb, f_wih, f_bih, s_wih, s_bih, gi_f, gi_s);
    msd_f2h_kernel<<<(1536 * DD / 4 + 255) / 256, 256, 0, stream>>>(f_whh, wfh, 1536 * DD / 4);
    msd_f2h_kernel<<<(1536 * DD / 4 + 255) / 256, 256, 0, stream>>>(s_whh, wsh, 1536 * DD / 4);
    msd_f2h_kernel<<<(DD * 1024 / 4 + 255) / 256, 256, 0, stream>>>(gw, gwh, DD * 1024 / 4);
    msd_init_kernel<<<(B * DD + 255) / 256, 256, 0, stream>>>(z_init, zf32, zs32a, zf16, zs16a, B * DD);

    float*    zs32c = zs32a; float*    zs32n = zs32b;
    _Float16* zs16c = zs16a; _Float16* zs16n = zs16b;
    for (int t = 0; t < T; ++t) {
        const int upd = ((t & 1) == 0) ? 1 : 0;
        k_gru<<<dim3(256, 1 + upd), 256, 0, stream>>>(
            zf16, zf32, zs16c, zs32c, wfh, wsh, f_bhh, s_bhh,
            gi_f + (size_t)t * 1536, gi_s + (size_t)t * 1536,
            zfn16, zs16n, zs32n);
        if (upd) {
            float* t1 = zs32c; zs32c = zs32n; zs32n = t1;
            _Float16* t2 = zs16c; zs16c = zs16n; zs16n = t2;
        }
        k_gate_ln<<<B / 16, 512, 0, stream>>>(
            zfn16, zs16c, zs32c, gwh, gb, gamma, beta,
            zf32, zf16, out, T, t);
    }
}